// Round 1
// baseline (185.750 us; speedup 1.0000x reference)
//
#include <hip/hip_runtime.h>

// InnerProduct: lp[r,p] = sum_f w[p,f]^2 * sum_e x[r,f,e]^2
// R=32768, F=64, E=16, P=10. Memory-bound: one coalesced pass over x (128 MiB).
constexpr int F = 64;
constexpr int E = 16;
constexpr int P = 10;

// One wave (64 lanes) per row. Row = F*E = 1024 floats = 64 lanes x 4 float4.
// Lane i, float4 seg: covers f = seg*16 + (i>>2), e in [4*(i&3), 4*(i&3)+4).
__global__ __launch_bounds__(256, 8) void ip_kernel(const float* __restrict__ x,
                                                    const float* __restrict__ w,
                                                    float* __restrict__ out,
                                                    int rows) {
    const int lane = threadIdx.x & 63;
    const int wave_in_block = threadIdx.x >> 6;
    const int waves_per_block = blockDim.x >> 6;
    const int wave_id = blockIdx.x * waves_per_block + wave_in_block;
    const int n_waves = gridDim.x * waves_per_block;

    const int q = lane & 3;   // e-quad index; also selects p = q + 4j
    const int g = lane >> 2;  // f mod 16

    // Preload squared weights once per wave (hoisted out of row loop).
    // wsq[j][seg] = w[q+4j, seg*16+g]^2 (0 when p >= P).
    float wsq[3][4];
#pragma unroll
    for (int j = 0; j < 3; ++j) {
        const int p = q + 4 * j;
#pragma unroll
        for (int seg = 0; seg < 4; ++seg) {
            const float wv = (p < P) ? w[p * F + seg * 16 + g] : 0.0f;
            wsq[j][seg] = wv * wv;
        }
    }

    for (int r = wave_id; r < rows; r += n_waves) {
        const float4* xrow = (const float4*)(x + (size_t)r * (F * E));
        float4 v[4];
#pragma unroll
        for (int seg = 0; seg < 4; ++seg)
            v[seg] = xrow[seg * 64 + lane];  // fully coalesced, 1 KiB/instr

        float acc0 = 0.0f, acc1 = 0.0f, acc2 = 0.0f;
#pragma unroll
        for (int seg = 0; seg < 4; ++seg) {
            const float4 t = v[seg];
            float sq = t.x * t.x + t.y * t.y + t.z * t.z + t.w * t.w;
            // combine the 4 e-quads -> full x_sq[f] in every lane of the group
            sq += __shfl_xor(sq, 1);
            sq += __shfl_xor(sq, 2);
            acc0 += wsq[0][seg] * sq;
            acc1 += wsq[1][seg] * sq;
            acc2 += wsq[2][seg] * sq;
        }
        // sum over the 16 f-groups (toggle g bits; q preserved)
#pragma unroll
        for (int m = 4; m <= 32; m <<= 1) {
            acc0 += __shfl_xor(acc0, m);
            acc1 += __shfl_xor(acc1, m);
            acc2 += __shfl_xor(acc2, m);
        }
        if (g == 0) {
            float* o = out + (size_t)r * P + q;
            o[0] = acc0;        // p = q
            o[4] = acc1;        // p = q + 4
            if (q < 2) o[8] = acc2;  // p = q + 8 (only 8,9 valid)
        }
    }
}

extern "C" void kernel_launch(void* const* d_in, const int* in_sizes, int n_in,
                              void* d_out, int out_size, void* d_ws, size_t ws_size,
                              hipStream_t stream) {
    const float* x = (const float*)d_in[0];
    const float* w = (const float*)d_in[1];
    float* out = (float*)d_out;
    const int rows = in_sizes[0] / (F * E);  // 32768

    // 2048 blocks x 256 threads = 8192 waves -> 4 rows/wave grid-stride,
    // 8 blocks/CU = 32 waves/CU for max latency hiding.
    dim3 grid(2048), block(256);
    hipLaunchKernelGGL(ip_kernel, grid, block, 0, stream, x, w, out, rows);
}